// Round 9
// baseline (342.936 us; speedup 1.0000x reference)
//
#include <hip/hip_runtime.h>

#define NN 14
#define EE 182

typedef __attribute__((ext_vector_type(8))) short bf16x8;
typedef __attribute__((ext_vector_type(4))) short bf16x4;
typedef __attribute__((ext_vector_type(4))) float f32x4;
typedef __attribute__((ext_vector_type(4))) unsigned u32x4;
typedef __attribute__((ext_vector_type(2))) unsigned u32x2;

__device__ __forceinline__ unsigned f2bf(float f) {            // RNE (prep only)
    unsigned u = __float_as_uint(f);
    return (u + 0x7fffu + ((u >> 16) & 1u)) >> 16;
}
// pack two f32 -> bf16 pair (round-half-away): add,add,v_perm = 3 VALU
__device__ __forceinline__ unsigned pack2bf(float lo, float hi) {
    return __builtin_amdgcn_perm(__float_as_uint(hi) + 0x8000u,
                                 __float_as_uint(lo) + 0x8000u, 0x07060302u);
}
__device__ __forceinline__ bf16x8 mk8(unsigned a, unsigned b, unsigned c, unsigned d) {
    u32x4 u = {a, b, c, d};
    return __builtin_bit_cast(bf16x8, u);
}
__device__ __forceinline__ bf16x4 mk4(unsigned a, unsigned b) {
    u32x2 u = {a, b};
    return __builtin_bit_cast(bf16x4, u);
}

// ---------------------------------------------------------------------------
// Weight pre-pack (every launch; d_ws re-poisoned each call).
// wp1/wp2 : W -> MFMA B-frag order: idx = ((tile*KK+kk)*64+L)*8+j,
//           value = W[kk*32+(L>>4)*8+j][tile*16+(L&15)]   (tile = h*4+ct)
// battn1/2: B-frag of (W[:,h*64:+64] @ a[h]); col n = which*4+h, n>=8 -> 0
// wcombT  : [c 64][n 16] = Wl[(n*64+c),:].Wpred, rows n>=14 zero;
//           wcombT[1024] = bl.Wpred + bp
// ---------------------------------------------------------------------------
__global__ void prep_pack(const float* __restrict__ W1, const float* __restrict__ W2,
                          const float* __restrict__ Wl, const float* __restrict__ Wpred,
                          const float* __restrict__ bl, const float* __restrict__ bp,
                          const float* __restrict__ as1, const float* __restrict__ ad1,
                          const float* __restrict__ as2, const float* __restrict__ ad2,
                          short* __restrict__ wp1, short* __restrict__ wp2,
                          short* __restrict__ battn1, short* __restrict__ battn2,
                          float* __restrict__ wcombT) {
    int gid = blockIdx.x * 256 + threadIdx.x;
    if (gid < 32768) {
        int j = gid & 7, L = (gid >> 3) & 63, kk = (gid >> 9) & 3, nt = gid >> 11;
        int k = kk * 32 + (L >> 4) * 8 + j, n = nt * 16 + (L & 15);
        wp1[gid] = (short)f2bf(W1[k * 256 + n]);
    } else if (gid < 49152) {
        int g2 = gid - 32768;
        int j = g2 & 7, L = (g2 >> 3) & 63, kk = (g2 >> 9) & 1, nt = g2 >> 10;
        int k = kk * 32 + (L >> 4) * 8 + j, n = nt * 16 + (L & 15);
        wp2[g2] = (short)f2bf(W2[k * 256 + n]);
    } else if (gid < 51200) {
        int g2 = gid - 49152;                 // (kk*64+L)*8+j, kk<4
        int j = g2 & 7, L = (g2 >> 3) & 63, kk = g2 >> 9;
        int n = L & 15, k = kk * 32 + (L >> 4) * 8 + j;
        float val = 0.f;
        if (n < 8) {
            const float* av = ((n >> 2) ? ad1 : as1) + (n & 3) * 64;
            const float* wr = W1 + k * 256 + (n & 3) * 64;
            for (int c = 0; c < 64; ++c) val += wr[c] * av[c];
        }
        battn1[g2] = (short)f2bf(val);
    } else if (gid < 52224) {
        int g2 = gid - 51200;                 // kk<2
        int j = g2 & 7, L = (g2 >> 3) & 63, kk = g2 >> 9;
        int n = L & 15, k = kk * 32 + (L >> 4) * 8 + j;
        float val = 0.f;
        if (n < 8) {
            const float* av = ((n >> 2) ? ad2 : as2) + (n & 3) * 64;
            const float* wr = W2 + k * 256 + (n & 3) * 64;
            for (int c = 0; c < 64; ++c) val += wr[c] * av[c];
        }
        battn2[g2] = (short)f2bf(val);
    } else if (gid < 53248) {
        int o = gid - 52224;                  // c*16 + n
        int n = o & 15, c = o >> 4;
        float acc = 0.f;
        if (n < NN) {
            const float* wr = Wl + (n * 64 + c) * 32;
            #pragma unroll
            for (int j = 0; j < 32; ++j) acc += wr[j] * Wpred[j];
        }
        wcombT[o] = acc;
    } else if (gid == 53248) {
        float acc = bp[0];
        #pragma unroll
        for (int j = 0; j < 32; ++j) acc += bl[j] * Wpred[j];
        wcombT[1024] = acc;
    }
}

// ---------------------------------------------------------------------------
// One GAT layer, fully in-wave, per-head pipeline:
//   GEMM tile (16x16x32, B-frags from wpB) -> pack2bf = agg B-frag (K=16)
//   P A-frag: 4 exps/lane (k = q*4+j), denom via 2 shfl_xor
//   agg: out[dst][chan] += mfma_16x16x16bf16_1k(P, Hfrag)
// RELU path: bias+relu, zero pad rows, write f32 to x2f[node][chan str 68].
// else: o[ct] = agg[ct] + bias (chan in lane&15, dst in q*4+r).
// ---------------------------------------------------------------------------
template<int KK, bool RELU>
__device__ __forceinline__ void gat_layer(int lane,
    const bf16x8* a, const short* wpB,
    const float* __restrict__ bias,
    const float* cntf, const float* alsd,
    float* x2f, f32x4* o)
{
    const int m = lane & 15, q = lane >> 4;
    f32x4 agg[4];
    #pragma unroll
    for (int ct = 0; ct < 4; ++ct) agg[ct] = f32x4{0.f, 0.f, 0.f, 0.f};

    #pragma unroll
    for (int h = 0; h < 4; ++h) {
        // ---- GEMM: 4 chan-tiles of this head; packs ARE the agg B-frags ----
        unsigned hf[4][2];
        #pragma unroll
        for (int ct = 0; ct < 4; ++ct) {
            f32x4 c = f32x4{0.f, 0.f, 0.f, 0.f};
            #pragma unroll
            for (int kk = 0; kk < KK; ++kk) {
                bf16x8 b = *(const bf16x8*)(wpB +
                    (((h * 4 + ct) * KK + kk) * 64 + lane) * 8);
                c = __builtin_amdgcn_mfma_f32_16x16x32_bf16(a[kk], b, c, 0, 0, 0);
            }
            hf[ct][0] = pack2bf(c[0], c[1]);
            hf[ct][1] = pack2bf(c[2], c[3]);
        }

        // ---- P A-frag: P[d=m][s=q*4+j] = cnt*exp(leaky(als[h][s]+ald[h][d]))/Z
        f32x4 alv = *(const f32x4*)(alsd + h * 16 + q * 4);
        float ad  = alsd[64 + h * 16 + m];
        f32x4 cv  = *(const f32x4*)(cntf + m * 20 + q * 4);
        float v0, v1, v2, v3;
        {
            float l0 = alv[0] + ad, l1 = alv[1] + ad, l2 = alv[2] + ad, l3 = alv[3] + ad;
            l0 = fmaxf(l0, 0.f) + 0.2f * fminf(l0, 0.f);
            l1 = fmaxf(l1, 0.f) + 0.2f * fminf(l1, 0.f);
            l2 = fmaxf(l2, 0.f) + 0.2f * fminf(l2, 0.f);
            l3 = fmaxf(l3, 0.f) + 0.2f * fminf(l3, 0.f);
            v0 = __expf(l0) * cv[0]; v1 = __expf(l1) * cv[1];
            v2 = __expf(l2) * cv[2]; v3 = __expf(l3) * cv[3];
        }
        float s = v0 + v1 + v2 + v3;
        s += __shfl_xor(s, 16);
        s += __shfl_xor(s, 32);
        float inv = (s > 0.f) ? 0.25f / s : 0.f;
        bf16x4 P = mk4(pack2bf(v0 * inv, v1 * inv), pack2bf(v2 * inv, v3 * inv));

        // ---- agg: out[dst][chan] += P @ H  (K=16, one head) ----
        #pragma unroll
        for (int ct = 0; ct < 4; ++ct)
            agg[ct] = __builtin_amdgcn_mfma_f32_16x16x16bf16_1k(
                P, mk4(hf[ct][0], hf[ct][1]), agg[ct], 0, 0, 0);
    }

    // ---- epilogue ----
    #pragma unroll
    for (int ct = 0; ct < 4; ++ct) {
        float bb = bias[ct * 16 + m];
        if (RELU) {
            #pragma unroll
            for (int r = 0; r < 4; ++r) {
                float v = fmaxf(agg[ct][r] + bb, 0.f);
                if (q * 4 + r >= NN) v = 0.f;
                x2f[(q * 4 + r) * 68 + ct * 16 + m] = v;
            }
        } else {
            o[ct] = f32x4{agg[ct][0] + bb, agg[ct][1] + bb,
                          agg[ct][2] + bb, agg[ct][3] + bb};
        }
    }
}

// ---------------------------------------------------------------------------
// Persistent blocks: 1024 thr (16 waves), 1 block/CU, 4 graphs/wave.
// wp1 streams from L2 (VMEM pipe); wp2+battn staged in LDS (DS pipe).
// ---------------------------------------------------------------------------
__global__ __launch_bounds__(1024, 4) void gat_fused(
    const float* __restrict__ feature,   // [B,14,128]
    const int*   __restrict__ edge_list, // [B,182,2] int32
    const float* __restrict__ b1, const float* __restrict__ b2,
    const short* __restrict__ wp1,       // W1 B-frags (L2 stream)
    const short* __restrict__ wpck,      // wp2|battn1|battn2 (19456 shorts)
    const float* __restrict__ wcombT,    // [1025]
    float* __restrict__ out, int B)
{
    const int w = threadIdx.x >> 6, lane = threadIdx.x & 63;
    const int m = lane & 15, q = lane >> 4;

    __shared__ __align__(16) short    swts[19456];      // 38912 B: wp2+battn
    __shared__ __align__(16) unsigned slab[16 * 448];   // 28672 B: cntf+alsd per wave
    __shared__ __align__(16) float    x2f_all[16 * 1088]; // 69632 B: [node16][chan68]/wave

    float* cntf = (float*)(slab + w * 448);             // [16 dst][20] counts
    float* alsd = (float*)(slab + w * 448 + 320);       // [2][4][16]
    float* x2f  = x2f_all + w * 1088;

    // ---- stage wp2+battn into LDS (once; the only barrier) ----
    {
        const u32x4* srcw = (const u32x4*)wpck;
        u32x4* dstw = (u32x4*)swts;
        #pragma unroll
        for (int r = 0; r < 3; ++r) {
            int i = r * 1024 + (int)threadIdx.x;
            if (i < 2432) dstw[i] = srcw[i];
        }
    }
    __syncthreads();

    const short* swp2  = swts;
    const short* sbat1 = swts + 16384;
    const short* sbat2 = swts + 18432;

    const int g0 = blockIdx.x * 64 + w * 4;

    #pragma clang loop unroll(disable)
    for (int it = 0; it < 4; ++it) {
        const int g = g0 + it;
        if (g >= B) break;

        // ---- cnt: zero + scatter edges + self loops (in-wave DS ordering) ----
        #pragma unroll
        for (int i = 0; i < 5; ++i) cntf[i * 64 + lane] = 0.f;
        {
            const int2* ep = (const int2*)edge_list + (size_t)g * EE;
            #pragma unroll
            for (int r = 0; r < 3; ++r) {
                int i = r * 64 + lane;
                if (i < EE) { int2 e = ep[i]; atomicAdd(&cntf[e.y * 20 + e.x], 1.f); }
            }
            if (lane < NN) atomicAdd(&cntf[lane * 21], 1.f);
        }

        // ---- layer-1 A-fragments from global (f32 -> bf16) ----
        bf16x8 a1[4];
        #pragma unroll
        for (int kk = 0; kk < 4; ++kk) a1[kk] = mk8(0, 0, 0, 0);
        if (m < NN) {
            const float* xg = feature + (size_t)g * (NN * 128) + m * 128;
            #pragma unroll
            for (int kk = 0; kk < 4; ++kk) {
                float4 v0 = *(const float4*)(xg + kk * 32 + q * 8);
                float4 v1 = *(const float4*)(xg + kk * 32 + q * 8 + 4);
                a1[kk] = mk8(pack2bf(v0.x, v0.y), pack2bf(v0.z, v0.w),
                             pack2bf(v1.x, v1.y), pack2bf(v1.z, v1.w));
            }
        }

        // ---- attn1 via MFMA (B staged in LDS) -> alsd ----
        {
            f32x4 ca = f32x4{0.f, 0.f, 0.f, 0.f};
            #pragma unroll
            for (int kk = 0; kk < 4; ++kk) {
                bf16x8 b = *(const bf16x8*)(sbat1 + (kk * 64 + lane) * 8);
                ca = __builtin_amdgcn_mfma_f32_16x16x32_bf16(a1[kk], b, ca, 0, 0, 0);
            }
            if (m < 8) *(f32x4*)(alsd + (m >> 2) * 64 + (m & 3) * 16 + q * 4) = ca;
        }

        // ---- layer 1 (relu) -> x2f ----
        gat_layer<4, true>(lane, a1, wp1, b1, cntf, alsd, x2f, nullptr);

        // ---- layer-2 A-frags from x2f (f32 -> bf16) ----
        bf16x8 a2[2];
        #pragma unroll
        for (int kk = 0; kk < 2; ++kk) {
            f32x4 lo = *(const f32x4*)(x2f + m * 68 + kk * 32 + q * 8);
            f32x4 hi = *(const f32x4*)(x2f + m * 68 + kk * 32 + q * 8 + 4);
            a2[kk] = mk8(pack2bf(lo[0], lo[1]), pack2bf(lo[2], lo[3]),
                         pack2bf(hi[0], hi[1]), pack2bf(hi[2], hi[3]));
        }

        // ---- attn2 -> alsd ----
        {
            f32x4 ca = f32x4{0.f, 0.f, 0.f, 0.f};
            #pragma unroll
            for (int kk = 0; kk < 2; ++kk) {
                bf16x8 b = *(const bf16x8*)(sbat2 + (kk * 64 + lane) * 8);
                ca = __builtin_amdgcn_mfma_f32_16x16x32_bf16(a2[kk], b, ca, 0, 0, 0);
            }
            if (m < 8) *(f32x4*)(alsd + (m >> 2) * 64 + (m & 3) * 16 + q * 4) = ca;
        }

        // ---- layer 2 -> o2 (chan = ct*16+m, dst = q*4+r) ----
        f32x4 o2[4];
        gat_layer<2, false>(lane, a2, swp2, b2, cntf, alsd, nullptr, o2);

        // ---- head: p = sum x3[n][c] * wcombT[c][n] ; sigmoid ----
        float p = 0.f;
        #pragma unroll
        for (int ct = 0; ct < 4; ++ct) {
            float4 wv = *(const float4*)(wcombT + (ct * 16 + m) * 16 + q * 4);
            p += o2[ct][0] * wv.x + o2[ct][1] * wv.y +
                 o2[ct][2] * wv.z + o2[ct][3] * wv.w;
        }
        p += __shfl_xor(p, 1);  p += __shfl_xor(p, 2);  p += __shfl_xor(p, 4);
        p += __shfl_xor(p, 8);  p += __shfl_xor(p, 16); p += __shfl_xor(p, 32);
        if (lane == 0) out[g] = 1.f / (1.f + __expf(-(p + wcombT[1024])));
    }
}

extern "C" void kernel_launch(void* const* d_in, const int* in_sizes, int n_in,
                              void* d_out, int out_size, void* d_ws, size_t ws_size,
                              hipStream_t stream) {
    const float* feature = (const float*)d_in[0];
    const int*   edges   = (const int*)d_in[1];
    const float* W1  = (const float*)d_in[2];
    const float* as1 = (const float*)d_in[3];
    const float* ad1 = (const float*)d_in[4];
    const float* b1  = (const float*)d_in[5];
    const float* W2  = (const float*)d_in[6];
    const float* as2 = (const float*)d_in[7];
    const float* ad2 = (const float*)d_in[8];
    const float* b2  = (const float*)d_in[9];
    const float* Wl  = (const float*)d_in[10];
    const float* bl  = (const float*)d_in[11];
    const float* Wp  = (const float*)d_in[12];
    const float* bp  = (const float*)d_in[13];
    float* out = (float*)d_out;

    short* wp1    = (short*)d_ws;            // 32768 sh
    short* wp2    = wp1 + 32768;             // 16384 sh
    short* battn1 = wp2 + 16384;             // 2048 sh
    short* battn2 = battn1 + 2048;           // 1024 sh  (wp2..battn2 contiguous)
    float* wcombT = (float*)(battn2 + 1024); // 1025 f32

    prep_pack<<<209, 256, 0, stream>>>(W1, W2, Wl, Wp, bl, bp, as1, ad1, as2, ad2,
                                       wp1, wp2, battn1, battn2, wcombT);

    const int B = in_sizes[0] / (NN * 128);
    gat_fused<<<(B + 63) / 64, 1024, 0, stream>>>(feature, edges, b1, b2,
                                                  wp1, wp2, wcombT, out, B);
}

// Round 10
// 231.941 us; speedup vs baseline: 1.4785x; 1.4785x over previous
//
#include <hip/hip_runtime.h>

#define NN 14
#define EE 182

typedef __attribute__((ext_vector_type(8))) short bf16x8;
typedef __attribute__((ext_vector_type(4))) short bf16x4;
typedef __attribute__((ext_vector_type(4))) float f32x4;
typedef __attribute__((ext_vector_type(4))) unsigned u32x4;
typedef __attribute__((ext_vector_type(2))) unsigned u32x2;

__device__ __forceinline__ unsigned f2bf(float f) {            // RNE (prep only)
    unsigned u = __float_as_uint(f);
    return (u + 0x7fffu + ((u >> 16) & 1u)) >> 16;
}
// pack two f32 -> bf16 pair (round-half-away): add,add,v_perm = 3 VALU
__device__ __forceinline__ unsigned pack2bf(float lo, float hi) {
    return __builtin_amdgcn_perm(__float_as_uint(hi) + 0x8000u,
                                 __float_as_uint(lo) + 0x8000u, 0x07060302u);
}
__device__ __forceinline__ bf16x8 mk8(unsigned a, unsigned b, unsigned c, unsigned d) {
    u32x4 u = {a, b, c, d};
    return __builtin_bit_cast(bf16x8, u);
}
__device__ __forceinline__ bf16x4 mk4(unsigned a, unsigned b) {
    u32x2 u = {a, b};
    return __builtin_bit_cast(bf16x4, u);
}

// ---------------------------------------------------------------------------
// Weight pre-pack (every launch; d_ws re-poisoned each call).
// wp1/wp2 : W -> MFMA B-frag order: idx = ((tile*KK+kk)*64+L)*8+j,
//           value = W[kk*32+(L>>4)*8+j][tile*16+(L&15)]   (tile = h*4+ct)
// battn1/2: B-frag of (W[:,h*64:+64] @ a[h]); col n = which*4+h, n>=8 -> 0
// wcombP  : head weights in the out2 lane layout:
//           wcombP[((ct*4+q)*16+m)*4+r] = (Wl@Wpred)[node=m][chan=ct*16+q*4+r],
//           rows m>=14 zero; wcombP[4096] = bl.Wpred + bp
// ---------------------------------------------------------------------------
__global__ void prep_pack(const float* __restrict__ W1, const float* __restrict__ W2,
                          const float* __restrict__ Wl, const float* __restrict__ Wpred,
                          const float* __restrict__ bl, const float* __restrict__ bp,
                          const float* __restrict__ as1, const float* __restrict__ ad1,
                          const float* __restrict__ as2, const float* __restrict__ ad2,
                          short* __restrict__ wp1, short* __restrict__ wp2,
                          short* __restrict__ battn1, short* __restrict__ battn2,
                          float* __restrict__ wcombP) {
    int gid = blockIdx.x * 256 + threadIdx.x;
    if (gid < 32768) {
        int j = gid & 7, L = (gid >> 3) & 63, kk = (gid >> 9) & 3, nt = gid >> 11;
        int k = kk * 32 + (L >> 4) * 8 + j, n = nt * 16 + (L & 15);
        wp1[gid] = (short)f2bf(W1[k * 256 + n]);
    } else if (gid < 49152) {
        int g2 = gid - 32768;
        int j = g2 & 7, L = (g2 >> 3) & 63, kk = (g2 >> 9) & 1, nt = g2 >> 10;
        int k = kk * 32 + (L >> 4) * 8 + j, n = nt * 16 + (L & 15);
        wp2[g2] = (short)f2bf(W2[k * 256 + n]);
    } else if (gid < 51200) {
        int g2 = gid - 49152;                 // (kk*64+L)*8+j, kk<4
        int j = g2 & 7, L = (g2 >> 3) & 63, kk = g2 >> 9;
        int n = L & 15, k = kk * 32 + (L >> 4) * 8 + j;
        float val = 0.f;
        if (n < 8) {
            const float* av = ((n >> 2) ? ad1 : as1) + (n & 3) * 64;
            const float* wr = W1 + k * 256 + (n & 3) * 64;
            for (int c = 0; c < 64; ++c) val += wr[c] * av[c];
        }
        battn1[g2] = (short)f2bf(val);
    } else if (gid < 52224) {
        int g2 = gid - 51200;                 // kk<2
        int j = g2 & 7, L = (g2 >> 3) & 63, kk = g2 >> 9;
        int n = L & 15, k = kk * 32 + (L >> 4) * 8 + j;
        float val = 0.f;
        if (n < 8) {
            const float* av = ((n >> 2) ? ad2 : as2) + (n & 3) * 64;
            const float* wr = W2 + k * 256 + (n & 3) * 64;
            for (int c = 0; c < 64; ++c) val += wr[c] * av[c];
        }
        battn2[g2] = (short)f2bf(val);
    } else if (gid < 56320) {
        int o = gid - 52224;                  // ((ct*4+q)*16+m)*4+r
        int r = o & 3, i4 = o >> 2;
        int m = i4 & 15, ctq = i4 >> 4;
        int q = ctq & 3, ct = ctq >> 2;
        int chan = ct * 16 + q * 4 + r;
        float acc = 0.f;
        if (m < NN) {
            const float* wr = Wl + (m * 64 + chan) * 32;
            #pragma unroll
            for (int j = 0; j < 32; ++j) acc += wr[j] * Wpred[j];
        }
        wcombP[o] = acc;
    } else if (gid == 56320) {
        float acc = bp[0];
        #pragma unroll
        for (int j = 0; j < 32; ++j) acc += bl[j] * Wpred[j];
        wcombP[4096] = acc;
    }
}

// ---------------------------------------------------------------------------
// One GAT layer, fully in-wave. Per head h:
//   GEMM tiles (16x16x32, B from LDS) -> pack2bf -> hf = A-frag of agg (K=16)
//   P frag (B-layout, = R9's P): P[dst=m][src=q*4+j], denom via 2 shfl
//   agg[ct] += mfma_16x16x16bf16_1k(hf, P)   -> out2[chan=q*4+r rows][dst=m cols]
// Epilogue: bias[chan] (+relu). RELU: pack po[ct][2] u32 (chans pairs), zero
// node lanes m>=14. Else: o[ct] f32 (+bias) for the head dot.
// ---------------------------------------------------------------------------
template<int KK, bool RELU>
__device__ __forceinline__ void gat_layer(int lane,
    const bf16x8* a, const short* wpB,
    const float* __restrict__ bias,
    const float* cntf, const float* alsd,
    f32x4* o, unsigned (*po)[2])
{
    const int m = lane & 15, q = lane >> 4;
    f32x4 agg[4];
    #pragma unroll
    for (int ct = 0; ct < 4; ++ct) agg[ct] = f32x4{0.f, 0.f, 0.f, 0.f};

    #pragma unroll
    for (int h = 0; h < 4; ++h) {
        // ---- GEMM: 4 chan-tiles of this head; packs ARE the agg A-frags ----
        unsigned hf[4][2];
        #pragma unroll
        for (int ct = 0; ct < 4; ++ct) {
            f32x4 c = f32x4{0.f, 0.f, 0.f, 0.f};
            #pragma unroll
            for (int kk = 0; kk < KK; ++kk) {
                bf16x8 b = *(const bf16x8*)(wpB +
                    (((h * 4 + ct) * KK + kk) * 64 + lane) * 8);
                c = __builtin_amdgcn_mfma_f32_16x16x32_bf16(a[kk], b, c, 0, 0, 0);
            }
            hf[ct][0] = pack2bf(c[0], c[1]);
            hf[ct][1] = pack2bf(c[2], c[3]);
        }

        // ---- P frag: P[d=m][s=q*4+j] = cnt*exp(leaky(als[h][s]+ald[h][d]))/Z
        f32x4 alv = *(const f32x4*)(alsd + h * 16 + q * 4);
        float ad  = alsd[64 + h * 16 + m];
        f32x4 cv  = *(const f32x4*)(cntf + m * 20 + q * 4);
        float v0, v1, v2, v3;
        {
            float l0 = alv[0] + ad, l1 = alv[1] + ad, l2 = alv[2] + ad, l3 = alv[3] + ad;
            l0 = fmaxf(l0, 0.f) + 0.2f * fminf(l0, 0.f);
            l1 = fmaxf(l1, 0.f) + 0.2f * fminf(l1, 0.f);
            l2 = fmaxf(l2, 0.f) + 0.2f * fminf(l2, 0.f);
            l3 = fmaxf(l3, 0.f) + 0.2f * fminf(l3, 0.f);
            v0 = __expf(l0) * cv[0]; v1 = __expf(l1) * cv[1];
            v2 = __expf(l2) * cv[2]; v3 = __expf(l3) * cv[3];
        }
        float s = v0 + v1 + v2 + v3;
        s += __shfl_xor(s, 16);
        s += __shfl_xor(s, 32);
        float inv = (s > 0.f) ? 0.25f / s : 0.f;
        bf16x4 P = mk4(pack2bf(v0 * inv, v1 * inv), pack2bf(v2 * inv, v3 * inv));

        // ---- agg (operand-swapped): out2[chan][dst] += H^T @ P^T ----
        #pragma unroll
        for (int ct = 0; ct < 4; ++ct)
            agg[ct] = __builtin_amdgcn_mfma_f32_16x16x16bf16_1k(
                mk4(hf[ct][0], hf[ct][1]), P, agg[ct], 0, 0, 0);
    }

    // ---- epilogue: bias[chan = ct*16+q*4+r] (+relu) ----
    #pragma unroll
    for (int ct = 0; ct < 4; ++ct) {
        float4 bb = *(const float4*)(bias + ct * 16 + q * 4);
        float o0 = agg[ct][0] + bb.x, o1 = agg[ct][1] + bb.y;
        float o2 = agg[ct][2] + bb.z, o3 = agg[ct][3] + bb.w;
        if (RELU) {
            o0 = fmaxf(o0, 0.f); o1 = fmaxf(o1, 0.f);
            o2 = fmaxf(o2, 0.f); o3 = fmaxf(o3, 0.f);
            if (m >= NN) { o0 = 0.f; o1 = 0.f; o2 = 0.f; o3 = 0.f; }  // pad nodes
            po[ct][0] = pack2bf(o0, o1);
            po[ct][1] = pack2bf(o2, o3);
        } else {
            o[ct] = f32x4{o0, o1, o2, o3};
        }
    }
}

// ---------------------------------------------------------------------------
// Persistent blocks: 1024 thr (16 waves), 1 block/CU, 4 graphs/wave.
// ALL weights staged in LDS once (104448 B); one barrier total.
// (1024,4): 128-VGPR budget (spill cliff below ~85, R5; global-stream
// load-queues blew it in R9 -- hence all-LDS).
// ---------------------------------------------------------------------------
__global__ __launch_bounds__(1024, 4) void gat_fused(
    const float* __restrict__ feature,   // [B,14,128]
    const int*   __restrict__ edge_list, // [B,182,2] int32
    const float* __restrict__ b1, const float* __restrict__ b2,
    const short* __restrict__ wpck,      // wp1|wp2|battn1|battn2 (52224 shorts)
    const float* __restrict__ wcombP,    // [4097]
    float* __restrict__ out, int B)
{
    const int w = threadIdx.x >> 6, lane = threadIdx.x & 63;
    const int m = lane & 15, q = lane >> 4;

    __shared__ __align__(16) short    swts[52224];     // 104448 B: all weights
    __shared__ __align__(16) unsigned slab[16 * 448];  // 28672 B: cntf+alsd per wave

    float* cntf = (float*)(slab + w * 448);            // [16 dst][20] counts
    float* alsd = (float*)(slab + w * 448 + 320);      // [2][4][16]

    // ---- stage all packed weights into LDS (once; the only barrier) ----
    {
        const u32x4* srcw = (const u32x4*)wpck;
        u32x4* dstw = (u32x4*)swts;
        #pragma unroll
        for (int r = 0; r < 7; ++r) {
            int i = r * 1024 + (int)threadIdx.x;
            if (i < 6528) dstw[i] = srcw[i];
        }
    }
    __syncthreads();

    const short* swp1  = swts;
    const short* swp2  = swts + 32768;
    const short* sbat1 = swts + 49152;
    const short* sbat2 = swts + 51200;

    const int g0 = blockIdx.x * 64 + w * 4;

    #pragma clang loop unroll(disable)
    for (int it = 0; it < 4; ++it) {
        const int g = g0 + it;
        if (g >= B) break;

        // ---- cnt: zero + scatter edges + self loops (in-wave DS ordering) ----
        #pragma unroll
        for (int i = 0; i < 5; ++i) cntf[i * 64 + lane] = 0.f;
        {
            const int2* ep = (const int2*)edge_list + (size_t)g * EE;
            #pragma unroll
            for (int r = 0; r < 3; ++r) {
                int i = r * 64 + lane;
                if (i < EE) { int2 e = ep[i]; atomicAdd(&cntf[e.y * 20 + e.x], 1.f); }
            }
            if (lane < NN) atomicAdd(&cntf[lane * 21], 1.f);
        }

        // ---- layer-1 A-fragments from global (f32 -> bf16) ----
        bf16x8 a1[4];
        #pragma unroll
        for (int kk = 0; kk < 4; ++kk) a1[kk] = mk8(0, 0, 0, 0);
        if (m < NN) {
            const float* xg = feature + (size_t)g * (NN * 128) + m * 128;
            #pragma unroll
            for (int kk = 0; kk < 4; ++kk) {
                float4 v0 = *(const float4*)(xg + kk * 32 + q * 8);
                float4 v1 = *(const float4*)(xg + kk * 32 + q * 8 + 4);
                a1[kk] = mk8(pack2bf(v0.x, v0.y), pack2bf(v0.z, v0.w),
                             pack2bf(v1.x, v1.y), pack2bf(v1.z, v1.w));
            }
        }

        // ---- attn1 via MFMA (B staged in LDS) -> alsd ----
        {
            f32x4 ca = f32x4{0.f, 0.f, 0.f, 0.f};
            #pragma unroll
            for (int kk = 0; kk < 4; ++kk) {
                bf16x8 b = *(const bf16x8*)(sbat1 + (kk * 64 + lane) * 8);
                ca = __builtin_amdgcn_mfma_f32_16x16x32_bf16(a1[kk], b, ca, 0, 0, 0);
            }
            if (m < 8) *(f32x4*)(alsd + (m >> 2) * 64 + (m & 3) * 16 + q * 4) = ca;
        }

        // ---- layer 1 (relu) -> po1: lane(m=node-col? no: chan rows) ----
        // po1[ct] holds chans ct*16+q*4+{0,1},{2,3} of node m, bf16-packed.
        unsigned po1[4][2];
        gat_layer<4, true>(lane, a1, swp1, b1, cntf, alsd, nullptr, po1);

        // ---- layer2 A-frags: 16-bpermute transpose of po1 ----
        // target a2[kk] chans kk*32+q*8+j of node m; source lane (q&1)*32+m
        // (j 0..3) and +16 (j 4..7), reg set ct = 2kk + (q>>1).
        bf16x8 a2[2];
        {
            int ad0 = ((q & 1) * 32 + m) * 4;
            int ad1_ = ad0 + 64;
            bool hi = (q >> 1) != 0;
            #pragma unroll
            for (int kk = 0; kk < 2; ++kk) {
                unsigned sA0 = __builtin_amdgcn_ds_bpermute(ad0, (int)po1[2 * kk][0]);
                unsigned sA1 = __builtin_amdgcn_ds_bpermute(ad0, (int)po1[2 * kk][1]);
                unsigned sB0 = __builtin_amdgcn_ds_bpermute(ad0, (int)po1[2 * kk + 1][0]);
                unsigned sB1 = __builtin_amdgcn_ds_bpermute(ad0, (int)po1[2 * kk + 1][1]);
                unsigned tA0 = __builtin_amdgcn_ds_bpermute(ad1_, (int)po1[2 * kk][0]);
                unsigned tA1 = __builtin_amdgcn_ds_bpermute(ad1_, (int)po1[2 * kk][1]);
                unsigned tB0 = __builtin_amdgcn_ds_bpermute(ad1_, (int)po1[2 * kk + 1][0]);
                unsigned tB1 = __builtin_amdgcn_ds_bpermute(ad1_, (int)po1[2 * kk + 1][1]);
                a2[kk] = mk8(hi ? sB0 : sA0, hi ? sB1 : sA1,
                             hi ? tB0 : tA0, hi ? tB1 : tA1);
            }
        }

        // ---- attn2 -> alsd ----
        {
            f32x4 ca = f32x4{0.f, 0.f, 0.f, 0.f};
            #pragma unroll
            for (int kk = 0; kk < 2; ++kk) {
                bf16x8 b = *(const bf16x8*)(sbat2 + (kk * 64 + lane) * 8);
                ca = __builtin_amdgcn_mfma_f32_16x16x32_bf16(a2[kk], b, ca, 0, 0, 0);
            }
            if (m < 8) *(f32x4*)(alsd + (m >> 2) * 64 + (m & 3) * 16 + q * 4) = ca;
        }

        // ---- layer 2 -> o2 (node = m lanes, chan = ct*16+q*4+r regs) ----
        f32x4 o2[4];
        gat_layer<2, false>(lane, a2, swp2, b2, cntf, alsd, o2, nullptr);

        // ---- head: p = sum o2 * wcombP (layout-matched) ; 64-lane reduce ----
        float p = 0.f;
        #pragma unroll
        for (int ct = 0; ct < 4; ++ct) {
            float4 wv = *(const float4*)(wcombP + ((ct * 4 + q) * 16 + m) * 4);
            p += o2[ct][0] * wv.x + o2[ct][1] * wv.y +
                 o2[ct][2] * wv.z + o2[ct][3] * wv.w;
        }
        p += __shfl_xor(p, 1);  p += __shfl_xor(p, 2);  p += __shfl_xor(p, 4);
        p += __shfl_xor(p, 8);  p += __shfl_xor(p, 16); p += __shfl_xor(p, 32);
        if (lane == 0) out[g] = 1.f / (1.f + __expf(-(p + wcombP[4096])));
    }
}

extern "C" void kernel_launch(void* const* d_in, const int* in_sizes, int n_in,
                              void* d_out, int out_size, void* d_ws, size_t ws_size,
                              hipStream_t stream) {
    const float* feature = (const float*)d_in[0];
    const int*   edges   = (const int*)d_in[1];
    const float* W1  = (const float*)d_in[2];
    const float* as1 = (const float*)d_in[3];
    const float* ad1 = (const float*)d_in[4];
    const float* b1  = (const float*)d_in[5];
    const float* W2  = (const float*)d_in[6];
    const float* as2 = (const float*)d_in[7];
    const float* ad2 = (const float*)d_in[8];
    const float* b2  = (const float*)d_in[9];
    const float* Wl  = (const float*)d_in[10];
    const float* bl  = (const float*)d_in[11];
    const float* Wp  = (const float*)d_in[12];
    const float* bp  = (const float*)d_in[13];
    float* out = (float*)d_out;

    short* wp1    = (short*)d_ws;            // 32768 sh
    short* wp2    = wp1 + 32768;             // 16384 sh
    short* battn1 = wp2 + 16384;             // 2048 sh
    short* battn2 = battn1 + 2048;           // 1024 sh  (wp1..battn2 contiguous)
    float* wcombP = (float*)(battn2 + 1024); // 4097 f32

    prep_pack<<<221, 256, 0, stream>>>(W1, W2, Wl, Wp, bl, bp, as1, ad1, as2, ad2,
                                       wp1, wp2, battn1, battn2, wcombP);

    const int B = in_sizes[0] / (NN * 128);
    gat_fused<<<(B + 63) / 64, 1024, 0, stream>>>(feature, edges, b1, b2,
                                                  wp1, wcombP, out, B);
}